// Round 2
// baseline (784.317 us; speedup 1.0000x reference)
//
#include <hip/hip_runtime.h>
#include <math.h>

#define S_LEN 2048
#define HID 4096
#define NH 32
#define NKV 8
#define HD 128
#define NQKV 6144

typedef __bf16 bf16x8 __attribute__((ext_vector_type(8)));
typedef float f32x4 __attribute__((ext_vector_type(4)));

__device__ inline short f2bf(float f) {
  union { float f; unsigned u; } a; a.f = f;
  unsigned r = a.u + 0x7fffu + ((a.u >> 16) & 1u);
  return (short)(r >> 16);
}

__device__ inline void glds16(const void* g, void* l) {
  __builtin_amdgcn_global_load_lds((const __attribute__((address_space(1))) void*)g,
                                   (__attribute__((address_space(3))) void*)l, 16, 0, 0);
}

template <int CTRL>
__device__ inline float dpp_max_step(float x) {
  int y = __builtin_amdgcn_update_dpp(0, __float_as_int(x), CTRL, 0xf, 0xf, false);
  return fmaxf(x, __int_as_float(y));
}

// ---------------- elementwise casts ----------------
__global__ __launch_bounds__(256) void cast_h(const float* __restrict__ X,
                                              short* __restrict__ Y, int n4) {
  int i = blockIdx.x * 256 + threadIdx.x;
  if (i >= n4) return;
  float4 v = ((const float4*)X)[i];
  short4 o;
  o.x = f2bf(v.x); o.y = f2bf(v.y); o.z = f2bf(v.z); o.w = f2bf(v.w);
  ((short4*)Y)[i] = o;
}

// W (4096 x Ncols) fp32 row-major  ->  Wt (Ncols x 4096) bf16
__global__ __launch_bounds__(256) void cast_wt(const float* __restrict__ W,
                                               short* __restrict__ Wt, int Ncols) {
  __shared__ float t[32][33];
  int n0 = blockIdx.x * 32, k0 = blockIdx.y * 32;
  int tx = threadIdx.x, ty = threadIdx.y;
  for (int j = 0; j < 4; j++)
    t[ty + 8 * j][tx] = W[(size_t)(k0 + ty + 8 * j) * Ncols + n0 + tx];
  __syncthreads();
  for (int j = 0; j < 4; j++)
    Wt[(size_t)(n0 + ty + 8 * j) * 4096 + k0 + tx] = f2bf(t[tx][ty + 8 * j]);
}

// ---------------- RoPE ----------------
__global__ void rope_table(const int* __restrict__ pos_ids, float* __restrict__ tc,
                           float* __restrict__ ts) {
  int p = blockIdx.x, i = threadIdx.x;
  float pos = (float)pos_ids[p];
  float inv = powf(10000.0f, -((float)(2 * i)) * (1.0f / 128.0f));
  float a = pos * inv;
  tc[p * 64 + i] = cosf(a);
  ts[p * 64 + i] = sinf(a);
}

__global__ void rope_apply(float* __restrict__ C, const float* __restrict__ tc,
                           const float* __restrict__ ts) {
  int p = blockIdx.x, hh = blockIdx.y, i = threadIdx.x;
  int col = (hh < 32) ? (hh * 128 + i) : (4096 + (hh - 32) * 128 + i);
  float c = tc[p * 64 + i], s = ts[p * 64 + i];
  float* row = C + (size_t)p * NQKV;
  float x1 = row[col], x2 = row[col + 64];
  row[col] = x1 * c - x2 * s;
  row[col + 64] = x2 * c + x1 * s;
}

// ---------------- absmax + quantize ----------------
__global__ __launch_bounds__(256) void absmax_k(const float* __restrict__ base, int bits,
                                                unsigned* __restrict__ slot) {
  const int n = 2048 << bits;
  const int mask = (1 << bits) - 1;
  float m = 0.f;
  for (int idx = blockIdx.x * blockDim.x + threadIdx.x; idx < n;
       idx += gridDim.x * blockDim.x)
    m = fmaxf(m, fabsf(base[(size_t)(idx >> bits) * NQKV + (idx & mask)]));
  for (int off = 32; off; off >>= 1) m = fmaxf(m, __shfl_xor(m, off, 64));
  __shared__ float red[4];
  if ((threadIdx.x & 63) == 0) red[threadIdx.x >> 6] = m;
  __syncthreads();
  if (threadIdx.x == 0) {
    m = fmaxf(fmaxf(red[0], red[1]), fmaxf(red[2], red[3]));
    atomicMax(slot, __float_as_uint(m));
  }
}

__global__ __launch_bounds__(256) void quant_q(const float* __restrict__ C,
                                               const unsigned* __restrict__ scal,
                                               short* __restrict__ Qi) {
  int idx = blockIdx.x * 256 + threadIdx.x;
  float scale = __uint_as_float(scal[0]) * (1.0f / 127.0f);
  int p = idx >> 12, c = idx & 4095;
  Qi[idx] = f2bf(rintf(C[(size_t)p * NQKV + c] / scale));
}

__global__ __launch_bounds__(256) void quant_k(const float* __restrict__ C,
                                               const unsigned* __restrict__ scal,
                                               short* __restrict__ Ki) {
  int idx = blockIdx.x * 256 + threadIdx.x;
  float scale = __uint_as_float(scal[1]) * (1.0f / 127.0f);
  int h = idx >> 18, p = (idx >> 7) & 2047, d = idx & 127;
  Ki[idx] = f2bf(rintf(C[(size_t)p * NQKV + 4096 + h * 128 + d] / scale));
}

__global__ __launch_bounds__(256) void quant_vt(const float* __restrict__ C,
                                                const unsigned* __restrict__ scal,
                                                short* __restrict__ Vt) {
  __shared__ float t[64][65];
  int h = blockIdx.x, pt = blockIdx.y, dt = blockIdx.z;
  float scale = __uint_as_float(scal[2]) * (1.0f / 127.0f);
  int tid = threadIdx.x;
  for (int j = 0; j < 16; j++) {
    int q = tid + 256 * j;
    int pl = q >> 6, dl = q & 63;
    t[dl][pl] = C[(size_t)(pt * 64 + pl) * NQKV + 5120 + h * 128 + dt * 64 + dl];
  }
  __syncthreads();
  for (int j = 0; j < 16; j++) {
    int q = tid + 256 * j;
    int dl = q >> 6, pl = q & 63;
    Vt[(size_t)(h * 128 + dt * 64 + dl) * 2048 + pt * 64 + pl] =
        f2bf(rintf(t[dl][pl] / scale));
  }
}

// ------- bf16 GEMM, C = A(MxK) * B^T(NxK), fp32 out, async LDS staging -------
__global__ __launch_bounds__(256) void gemm_bt(const short* __restrict__ A, int lda,
                                               const short* __restrict__ B,
                                               float* __restrict__ C, int ldc, int K) {
  __shared__ alignas(16) short As[128 * 32];
  __shared__ alignas(16) short Bs[128 * 32];
  const int tid = threadIdx.x;
  const int wave = tid >> 6, lane = tid & 63;
  const int quad = lane >> 4, l15 = lane & 15;
  const int m0 = blockIdx.y * 128, n0 = blockIdx.x * 128;
  const int wm = (wave >> 1) * 64, wn = (wave & 1) * 64;
  f32x4 acc[4][4] = {};
  const int sr = wave * 16 + (lane >> 2);  // rows 0..63 for issue 0
  const int sg = (lane & 3) * 8;
  const short* Ag0 = A + (size_t)(m0 + sr) * lda + sg;
  const short* Ag1 = A + (size_t)(m0 + 64 + sr) * lda + sg;
  const short* Bg0 = B + (size_t)(n0 + sr) * K + sg;
  const short* Bg1 = B + (size_t)(n0 + 64 + sr) * K + sg;
  short* Asl0 = &As[wave * 512];
  short* Asl1 = &As[(4 + wave) * 512];
  short* Bsl0 = &Bs[wave * 512];
  short* Bsl1 = &Bs[(4 + wave) * 512];
  for (int k0 = 0; k0 < K; k0 += 32) {
    __syncthreads();
    glds16(Ag0 + k0, Asl0);
    glds16(Ag1 + k0, Asl1);
    glds16(Bg0 + k0, Bsl0);
    glds16(Bg1 + k0, Bsl1);
    __syncthreads();
    bf16x8 af[4], bfr[4];
#pragma unroll
    for (int t = 0; t < 4; t++) {
      af[t] = *(const bf16x8*)&As[(wm + t * 16 + l15) * 32 + quad * 8];
      bfr[t] = *(const bf16x8*)&Bs[(wn + t * 16 + l15) * 32 + quad * 8];
    }
#pragma unroll
    for (int tm = 0; tm < 4; tm++)
#pragma unroll
      for (int tn = 0; tn < 4; tn++)
        acc[tm][tn] =
            __builtin_amdgcn_mfma_f32_16x16x32_bf16(af[tm], bfr[tn], acc[tm][tn], 0, 0, 0);
  }
#pragma unroll
  for (int tm = 0; tm < 4; tm++)
#pragma unroll
    for (int tn = 0; tn < 4; tn++) {
      const int row = m0 + wm + tm * 16 + quad * 4;
      const int col = n0 + wn + tn * 16 + l15;
#pragma unroll
      for (int r = 0; r < 4; r++) C[(size_t)(row + r) * ldc + col] = acc[tm][tn][r];
    }
}

// -------- fused causal GQA attention: 64-row q-tiles, paired (i, 31-i) --------
__global__ __launch_bounds__(256) void attn_fused(const short* __restrict__ Qi,
                                                  const short* __restrict__ Ki,
                                                  const short* __restrict__ Vt,
                                                  const unsigned* __restrict__ scal,
                                                  short* __restrict__ Oa) {
  __shared__ alignas(16) short Ks[64 * 136];    // [key][d]
  __shared__ alignas(16) short Vs[144 * 72];    // [d][key], rows 128..143 = ones
  __shared__ alignas(16) short Ps[4][16 * 72];  // per-wave P
  const int tid = threadIdx.x;
  const int wave = tid >> 6, lane = tid & 63;
  const int quad = lane >> 4, l15 = lane & 15;
  const int h = blockIdx.x & 31, pq = blockIdx.x >> 5;
  const int kvh = h >> 2;
  const float qs = __uint_as_float(scal[0]) * (1.0f / 127.0f);
  const float ksc = __uint_as_float(scal[1]) * (1.0f / 127.0f);
  const float vsc = __uint_as_float(scal[2]) * (1.0f / 127.0f);
  const float sscale = qs * ksc * 0.08838834764831845f * 1.4426950408889634f;  // /sqrt(128)*log2e
  const short* Kg = Ki + (size_t)kvh * S_LEN * HD;
  const short* Vg = Vt + (size_t)kvh * HD * S_LEN;
  int4* Ks4 = (int4*)Ks;
  int4* Vs4 = (int4*)Vs;

  for (int i = tid; i < 16 * 72; i += 256) Vs[128 * 72 + i] = 0x3F80;  // bf16 1.0

  const int kr = tid >> 4, ksg = tid & 15;  // K staging: row kr+16j, seg ksg
  const int vd = tid >> 3, vsg = tid & 7;   // V staging: d vd+32j, seg vsg

  int4 pk[4], pv[4];
#pragma unroll
  for (int j = 0; j < 4; j++)
    pk[j] = *(const int4*)(Kg + (size_t)(kr + 16 * j) * HD + ksg * 8);
#pragma unroll
  for (int j = 0; j < 4; j++)
    pv[j] = *(const int4*)(Vg + (size_t)(vd + 32 * j) * S_LEN + vsg * 8);

  for (int ph = 0; ph < 2; ph++) {
    const int qt = ph ? 31 - pq : pq;  // 64-row q-tile index, pair work = 33 tiles
    const int rw = qt * 64 + wave * 16;
    bf16x8 aq[4];
#pragma unroll
    for (int kc = 0; kc < 4; kc++)
      aq[kc] = *(const bf16x8*)(Qi + (size_t)(rw + l15) * 4096 + h * 128 + kc * 32 +
                                quad * 8);
    f32x4 o[9] = {};
    float m_[4] = {-INFINITY, -INFINITY, -INFINITY, -INFINITY};
    const int nkt = qt + 1;
    for (int kt = 0; kt < nkt; kt++) {
      const int k0 = kt * 64;
      __syncthreads();  // prior PV reads done before overwrite
#pragma unroll
      for (int j = 0; j < 4; j++) Ks4[(kr + 16 * j) * 17 + ksg] = pk[j];
#pragma unroll
      for (int j = 0; j < 4; j++) Vs4[(vd + 32 * j) * 9 + vsg] = pv[j];
      const int nx = (kt + 1 < nkt) ? k0 + 64 : 0;  // clamp->prefetch tile 0 for next phase
#pragma unroll
      for (int j = 0; j < 4; j++)
        pk[j] = *(const int4*)(Kg + (size_t)(nx + kr + 16 * j) * HD + ksg * 8);
#pragma unroll
      for (int j = 0; j < 4; j++)
        pv[j] = *(const int4*)(Vg + (size_t)(vd + 32 * j) * S_LEN + nx + vsg * 8);
      __syncthreads();  // staged tile visible

      f32x4 sf[4];
#pragma unroll
      for (int tn = 0; tn < 4; tn++) {
        f32x4 s = {0.f, 0.f, 0.f, 0.f};
#pragma unroll
        for (int kc = 0; kc < 4; kc++) {
          bf16x8 bk = *(const bf16x8*)&Ks[(tn * 16 + l15) * 136 + kc * 32 + quad * 8];
          s = __builtin_amdgcn_mfma_f32_16x16x32_bf16(aq[kc], bk, s, 0, 0, 0);
        }
        sf[tn] = s;
      }

      const bool diag = (kt == qt);  // only the last tile of a phase is partial
#pragma unroll
      for (int r = 0; r < 4; r++) {
        const int grow = rw + quad * 4 + r;
        float mx = -3.0e38f;
        if (diag) {
#pragma unroll
          for (int tn = 0; tn < 4; tn++) {
            float v = sf[tn][r] * sscale;
            if (k0 + tn * 16 + l15 > grow) v = -3.0e38f;
            sf[tn][r] = v;
            mx = fmaxf(mx, v);
          }
        } else {
#pragma unroll
          for (int tn = 0; tn < 4; tn++) {
            float v = sf[tn][r] * sscale;
            sf[tn][r] = v;
            mx = fmaxf(mx, v);
          }
        }
        mx = dpp_max_step<0x121>(mx);  // row_ror:1
        mx = dpp_max_step<0x122>(mx);  // row_ror:2
        mx = dpp_max_step<0x124>(mx);  // row_ror:4
        mx = dpp_max_step<0x128>(mx);  // row_ror:8
        const float mo = m_[r];
        const float mn = fmaxf(mo, mx);
        m_[r] = mn;
        const float alpha = __builtin_amdgcn_exp2f(mo - mn);
#pragma unroll
        for (int tn = 0; tn < 4; tn++) {
          float p = __builtin_amdgcn_exp2f(sf[tn][r] - mn);
          Ps[wave][(quad * 4 + r) * 72 + tn * 16 + l15] =
              (short)((__float_as_uint(p) + 0x8000u) >> 16);
        }
        if (__ballot(alpha != 1.0f)) {
#pragma unroll
          for (int t = 0; t < 9; t++) o[t][r] *= alpha;
        }
      }
      // Ps is wave-private: no barrier needed (compiler orders ds ops via lgkmcnt)
#pragma unroll
      for (int kk = 0; kk < 2; kk++) {
        bf16x8 ap = *(const bf16x8*)&Ps[wave][l15 * 72 + kk * 32 + quad * 8];
#pragma unroll
        for (int tn = 0; tn < 9; tn++) {
          bf16x8 bv = *(const bf16x8*)&Vs[(tn * 16 + l15) * 72 + kk * 32 + quad * 8];
          o[tn] = __builtin_amdgcn_mfma_f32_16x16x32_bf16(ap, bv, o[tn], 0, 0, 0);
        }
      }
    }
#pragma unroll
    for (int r = 0; r < 4; r++) {
      const int grow = rw + quad * 4 + r;
      const float sc = vsc / o[8][r];  // l arrived via the ones-column of V
#pragma unroll
      for (int tn = 0; tn < 8; tn++)
        Oa[(size_t)grow * 4096 + h * 128 + tn * 16 + l15] = f2bf(o[tn][r] * sc);
    }
  }
}

// ---------------- launch ----------------
extern "C" void kernel_launch(void* const* d_in, const int* in_sizes, int n_in,
                              void* d_out, int out_size, void* d_ws, size_t ws_size,
                              hipStream_t stream) {
  (void)in_sizes; (void)n_in; (void)out_size; (void)ws_size;
  const float* H  = (const float*)d_in[0];
  const int*   pos = (const int*)d_in[2];
  const float* wq = (const float*)d_in[3];
  const float* wk = (const float*)d_in[4];
  const float* wv = (const float*)d_in[5];
  const float* wo = (const float*)d_in[6];
  char* ws = (char*)d_ws;
  short* Hb   = (short*)(ws + 0);           // 16 MB
  short* Wt   = (short*)(ws + 16777216);    // 48 MB (6144 x 4096 bf16, qkv^T concat)
  short* Wot  = (short*)(ws + 67108864);    // 32 MB
  float* C    = (float*)(ws + 100663296);   // 48 MB (2048 x 6144 f32)
  short* Qi   = (short*)(ws + 150994944);   // 16 MB
  short* Ki   = (short*)(ws + 167772160);   // 4 MB (8,2048,128)
  short* Vt   = (short*)(ws + 171966464);   // 4 MB (8,128,2048)
  short* Oa   = (short*)(ws + 176160768);   // 16 MB
  float* tc   = (float*)(ws + 192937984);   // 512 KB
  float* tsn  = (float*)(ws + 193462272);   // 512 KB
  unsigned* scal = (unsigned*)(ws + 193986560);

  hipLaunchKernelGGL(cast_h, dim3(8192), dim3(256), 0, stream, H, Hb, 2097152);
  hipLaunchKernelGGL(cast_wt, dim3(128, 128), dim3(32, 8), 0, stream, wq, Wt, 4096);
  hipLaunchKernelGGL(cast_wt, dim3(32, 128), dim3(32, 8), 0, stream, wk,
                     Wt + (size_t)4096 * 4096, 1024);
  hipLaunchKernelGGL(cast_wt, dim3(32, 128), dim3(32, 8), 0, stream, wv,
                     Wt + (size_t)5120 * 4096, 1024);
  hipLaunchKernelGGL(cast_wt, dim3(128, 128), dim3(32, 8), 0, stream, wo, Wot, 4096);
  hipLaunchKernelGGL(rope_table, dim3(2048), dim3(64), 0, stream, pos, tc, tsn);
  hipLaunchKernelGGL(gemm_bt, dim3(48, 16), dim3(256), 0, stream, Hb, 4096, Wt, C, 6144,
                     4096);
  hipLaunchKernelGGL(rope_apply, dim3(2048, 40), dim3(64), 0, stream, C, tc, tsn);
  hipMemsetAsync(scal, 0, 16, stream);
  hipLaunchKernelGGL(absmax_k, dim3(1024), dim3(256), 0, stream, C, 12, scal + 0);
  hipLaunchKernelGGL(absmax_k, dim3(512), dim3(256), 0, stream, C + 4096, 10, scal + 1);
  hipLaunchKernelGGL(absmax_k, dim3(512), dim3(256), 0, stream, C + 5120, 10, scal + 2);
  hipLaunchKernelGGL(quant_q, dim3(32768), dim3(256), 0, stream, C, scal, Qi);
  hipLaunchKernelGGL(quant_k, dim3(8192), dim3(256), 0, stream, C, scal, Ki);
  hipLaunchKernelGGL(quant_vt, dim3(8, 32, 2), dim3(256), 0, stream, C, scal, Vt);
  hipLaunchKernelGGL(attn_fused, dim3(512), dim3(256), 0, stream, Qi, Ki, Vt, scal, Oa);
  hipLaunchKernelGGL(gemm_bt, dim3(32, 16), dim3(256), 0, stream, Oa, 4096, Wot,
                     (float*)d_out, 4096, 4096);
}

// Round 4
// 564.011 us; speedup vs baseline: 1.3906x; 1.3906x over previous
//
#include <hip/hip_runtime.h>
#include <math.h>

#define S_LEN 2048
#define HID 4096
#define NH 32
#define NKV 8
#define HD 128
#define NQKV 6144

typedef __bf16 bf16x8 __attribute__((ext_vector_type(8)));
typedef float f32x4 __attribute__((ext_vector_type(4)));
typedef short short8v __attribute__((ext_vector_type(8)));

__device__ inline short f2bf(float f) {
  union { float f; unsigned u; } a; a.f = f;
  unsigned r = a.u + 0x7fffu + ((a.u >> 16) & 1u);
  return (short)(r >> 16);
}

__device__ inline void glds16(const void* g, void* l) {
  __builtin_amdgcn_global_load_lds((const __attribute__((address_space(1))) void*)g,
                                   (__attribute__((address_space(3))) void*)l, 16, 0, 0);
}

template <int CTRL>
__device__ inline float dpp_max_step(float x) {
  int y = __builtin_amdgcn_update_dpp(0, __float_as_int(x), CTRL, 0xf, 0xf, false);
  return fmaxf(x, __int_as_float(y));
}

// ---------------- elementwise casts ----------------
__global__ __launch_bounds__(256) void cast_h(const float* __restrict__ X,
                                              short* __restrict__ Y, int n4) {
  int i = blockIdx.x * 256 + threadIdx.x;
  if (i >= n4) return;
  float4 v = ((const float4*)X)[i];
  short4 o;
  o.x = f2bf(v.x); o.y = f2bf(v.y); o.z = f2bf(v.z); o.w = f2bf(v.w);
  ((short4*)Y)[i] = o;
}

// W (4096 x Ncols) fp32 row-major  ->  Wt (Ncols x 4096) bf16
__global__ __launch_bounds__(256) void cast_wt(const float* __restrict__ W,
                                               short* __restrict__ Wt, int Ncols) {
  __shared__ float t[32][33];
  int n0 = blockIdx.x * 32, k0 = blockIdx.y * 32;
  int tx = threadIdx.x, ty = threadIdx.y;
  for (int j = 0; j < 4; j++)
    t[ty + 8 * j][tx] = W[(size_t)(k0 + ty + 8 * j) * Ncols + n0 + tx];
  __syncthreads();
  for (int j = 0; j < 4; j++)
    Wt[(size_t)(n0 + ty + 8 * j) * 4096 + k0 + tx] = f2bf(t[tx][ty + 8 * j]);
}

// ---------------- RoPE ----------------
__global__ void rope_table(const int* __restrict__ pos_ids, float* __restrict__ tc,
                           float* __restrict__ ts) {
  int p = blockIdx.x, i = threadIdx.x;
  float pos = (float)pos_ids[p];
  float inv = powf(10000.0f, -((float)(2 * i)) * (1.0f / 128.0f));
  float a = pos * inv;
  tc[p * 64 + i] = cosf(a);
  ts[p * 64 + i] = sinf(a);
}

// fused: apply RoPE to Q,K columns of C (in-place) + global absmax of Q,K,V
__global__ __launch_bounds__(256) void rope_absmax(float* __restrict__ C,
                                                   const float* __restrict__ tc,
                                                   const float* __restrict__ ts,
                                                   unsigned* __restrict__ scal) {
  __shared__ float lc[64], lsn[64];
  __shared__ float red[3][4];
  const int p = blockIdx.x, t = threadIdx.x;
  if (t < 64) { lc[t] = tc[p * 64 + t]; lsn[t] = ts[p * 64 + t]; }
  __syncthreads();
  float* row = C + (size_t)p * NQKV;
  float mq = 0.f, mk = 0.f, mv = 0.f;
#pragma unroll
  for (int j = 0; j < 8; j++) {  // Q: 32 heads x 64 = 2048 rotate-pairs
    int idx = t + 256 * j;
    int i = idx & 63, col = (idx >> 6) * 128 + i;
    float c = lc[i], s = lsn[i];
    float x1 = row[col], x2 = row[col + 64];
    float y1 = x1 * c - x2 * s, y2 = x2 * c + x1 * s;
    row[col] = y1; row[col + 64] = y2;
    mq = fmaxf(mq, fmaxf(fabsf(y1), fabsf(y2)));
  }
#pragma unroll
  for (int j = 0; j < 2; j++) {  // K: 8 heads x 64 = 512 rotate-pairs (j<2, NOT 4!)
    int idx = t + 256 * j;
    int i = idx & 63, col = 4096 + (idx >> 6) * 128 + i;
    float c = lc[i], s = lsn[i];
    float x1 = row[col], x2 = row[col + 64];
    float y1 = x1 * c - x2 * s, y2 = x2 * c + x1 * s;
    row[col] = y1; row[col + 64] = y2;
    mk = fmaxf(mk, fmaxf(fabsf(y1), fabsf(y2)));
  }
#pragma unroll
  for (int j = 0; j < 4; j++) {  // V: plain absmax over 1024 cols
    float v = row[5120 + t + 256 * j];
    mv = fmaxf(mv, fabsf(v));
  }
  for (int off = 32; off; off >>= 1) {
    mq = fmaxf(mq, __shfl_xor(mq, off, 64));
    mk = fmaxf(mk, __shfl_xor(mk, off, 64));
    mv = fmaxf(mv, __shfl_xor(mv, off, 64));
  }
  const int wave = t >> 6;
  if ((t & 63) == 0) { red[0][wave] = mq; red[1][wave] = mk; red[2][wave] = mv; }
  __syncthreads();
  if (t < 3) {
    float m = fmaxf(fmaxf(red[t][0], red[t][1]), fmaxf(red[t][2], red[t][3]));
    atomicMax(scal + t, __float_as_uint(m));
  }
}

// ---------------- quantize ----------------
__global__ __launch_bounds__(256) void quant_q(const float* __restrict__ C,
                                               const unsigned* __restrict__ scal,
                                               short* __restrict__ Qi) {
  int idx = blockIdx.x * 256 + threadIdx.x;
  float scale = __uint_as_float(scal[0]) * (1.0f / 127.0f);
  int p = idx >> 12, c = idx & 4095;
  Qi[idx] = f2bf(rintf(C[(size_t)p * NQKV + c] / scale));
}

__global__ __launch_bounds__(256) void quant_k(const float* __restrict__ C,
                                               const unsigned* __restrict__ scal,
                                               short* __restrict__ Ki) {
  int idx = blockIdx.x * 256 + threadIdx.x;
  float scale = __uint_as_float(scal[1]) * (1.0f / 127.0f);
  int h = idx >> 18, p = (idx >> 7) & 2047, d = idx & 127;
  Ki[idx] = f2bf(rintf(C[(size_t)p * NQKV + 4096 + h * 128 + d] / scale));
}

__global__ __launch_bounds__(256) void quant_vt(const float* __restrict__ C,
                                                const unsigned* __restrict__ scal,
                                                short* __restrict__ Vt) {
  __shared__ float t[64][65];
  int h = blockIdx.x, pt = blockIdx.y, dt = blockIdx.z;
  float scale = __uint_as_float(scal[2]) * (1.0f / 127.0f);
  int tid = threadIdx.x;
  for (int j = 0; j < 16; j++) {
    int q = tid + 256 * j;
    int pl = q >> 6, dl = q & 63;
    t[dl][pl] = C[(size_t)(pt * 64 + pl) * NQKV + 5120 + h * 128 + dt * 64 + dl];
  }
  __syncthreads();
  for (int j = 0; j < 16; j++) {
    int q = tid + 256 * j;
    int dl = q >> 6, pl = q & 63;
    Vt[(size_t)(h * 128 + dt * 64 + dl) * 2048 + pt * 64 + pl] =
        f2bf(rintf(t[dl][pl] / scale));
  }
}

// -- bf16 GEMM, C = A(MxK) * B^T(NxK): double-buffered glds16, 1 barrier/iter --
__global__ __launch_bounds__(256, 2) void gemm_bt(const short* __restrict__ A, int lda,
                                                  const short* __restrict__ B,
                                                  float* __restrict__ C, int ldc, int K) {
  __shared__ alignas(16) short As[2][4096];  // 128 rows x 32 (unpadded)
  __shared__ alignas(16) short Bs[2][4096];
  const int tid = threadIdx.x;
  const int wave = tid >> 6, lane = tid & 63;
  const int quad = lane >> 4, l15 = lane & 15;
  const int m0 = blockIdx.y * 128, n0 = blockIdx.x * 128;
  const int wm = (wave >> 1) * 64, wn = (wave & 1) * 64;
  f32x4 acc[4][4] = {};
  const int sr = wave * 16 + (lane >> 2);
  const int sg = (lane & 3) * 8;
  const short* Ag0 = A + (size_t)(m0 + sr) * lda + sg;
  const short* Ag1 = A + (size_t)(m0 + 64 + sr) * lda + sg;
  const short* Bg0 = B + (size_t)(n0 + sr) * K + sg;
  const short* Bg1 = B + (size_t)(n0 + 64 + sr) * K + sg;
  auto stage = [&](int kk, int b) {
    glds16(Ag0 + kk, &As[b][wave * 512]);
    glds16(Ag1 + kk, &As[b][2048 + wave * 512]);
    glds16(Bg0 + kk, &Bs[b][wave * 512]);
    glds16(Bg1 + kk, &Bs[b][2048 + wave * 512]);
  };
  stage(0, 0);
  int b = 0;
  for (int k0 = 0; k0 < K; k0 += 32) {
    __syncthreads();  // drains stage(k0) issued last iter; protects buf b^1
    const int nk = (k0 + 32 < K) ? k0 + 32 : k0;  // last iter: restage (unused)
    stage(nk, b ^ 1);
    bf16x8 af[4], bfr[4];
#pragma unroll
    for (int t = 0; t < 4; t++) {
      af[t] = *(const bf16x8*)&As[b][(wm + t * 16 + l15) * 32 + quad * 8];
      bfr[t] = *(const bf16x8*)&Bs[b][(wn + t * 16 + l15) * 32 + quad * 8];
    }
#pragma unroll
    for (int tm = 0; tm < 4; tm++)
#pragma unroll
      for (int tn = 0; tn < 4; tn++)
        acc[tm][tn] =
            __builtin_amdgcn_mfma_f32_16x16x32_bf16(af[tm], bfr[tn], acc[tm][tn], 0, 0, 0);
    b ^= 1;
  }
#pragma unroll
  for (int tm = 0; tm < 4; tm++)
#pragma unroll
    for (int tn = 0; tn < 4; tn++) {
      const int row = m0 + wm + tm * 16 + quad * 4;
      const int col = n0 + wn + tn * 16 + l15;
#pragma unroll
      for (int r = 0; r < 4; r++) C[(size_t)(row + r) * ldc + col] = acc[tm][tn][r];
    }
}

// ---- fused causal GQA attention: paired q-tiles, glds16 dbuf, XOR swizzle ----
__global__ __launch_bounds__(256, 2) void attn_fused(const short* __restrict__ Qi,
                                                     const short* __restrict__ Ki,
                                                     const short* __restrict__ Vt,
                                                     const unsigned* __restrict__ scal,
                                                     short* __restrict__ Oa) {
  __shared__ alignas(16) short Ks[2][64 * 128];   // [key][d], seg-swizzled
  __shared__ alignas(16) short Vs[2][128 * 64];   // [d][key], seg-swizzled
  __shared__ alignas(16) short Ps[4][16 * 72];    // per-wave P, padded
  const int tid = threadIdx.x;
  const int wave = tid >> 6, lane = tid & 63;
  const int quad = lane >> 4, l15 = lane & 15;
  const int swz = l15 & 7;
  const int h = blockIdx.x & 31, pq = blockIdx.x >> 5;
  const int kvh = h >> 2;
  const float qs = __uint_as_float(scal[0]) * (1.0f / 127.0f);
  const float ksc = __uint_as_float(scal[1]) * (1.0f / 127.0f);
  const float vsc = __uint_as_float(scal[2]) * (1.0f / 127.0f);
  const float sscale = qs * ksc * 0.08838834764831845f * 1.4426950408889634f;
  const short* Kg = Ki + (size_t)kvh * S_LEN * HD;
  const short* Vg = Vt + (size_t)kvh * HD * S_LEN;

  union { short8v s; bf16x8 b; } uone;
  uone.s = short8v{0x3F80, 0x3F80, 0x3F80, 0x3F80, 0x3F80, 0x3F80, 0x3F80, 0x3F80};
  const bf16x8 vone = uone.b;

  // staging slot -> swizzled global offsets (slot = j*256 + tid, 16B units)
  int koff[4], voff[4];
#pragma unroll
  for (int j = 0; j < 4; j++) {
    int slot = j * 256 + tid;
    int r = slot >> 4, seg = slot & 15;            // K: 64 rows x 16 segs
    koff[j] = r * 128 + ((seg ^ (r & 7)) * 8);
    int vr = slot >> 3, vseg = slot & 7;           // V: 128 rows x 8 segs
    voff[j] = vr * 2048 + ((vseg ^ (vr & 7)) * 8);
  }
  auto stage = [&](int k0, int b) {
#pragma unroll
    for (int j = 0; j < 4; j++)
      glds16(Kg + (size_t)k0 * HD + koff[j], &Ks[b][(j * 256 + wave * 64) * 8]);
#pragma unroll
    for (int j = 0; j < 4; j++)
      glds16(Vg + (size_t)k0 + voff[j], &Vs[b][(j * 256 + wave * 64) * 8]);
  };

  stage(0, 0);
  int buf = 0;
  for (int ph = 0; ph < 2; ph++) {
    const int qt = ph ? 31 - pq : pq;  // pair (i, 31-i): uniform 33 tiles/block
    const int rw = qt * 64 + wave * 16;
    bf16x8 aq[4];
#pragma unroll
    for (int kc = 0; kc < 4; kc++)
      aq[kc] = *(const bf16x8*)(Qi + (size_t)(rw + l15) * 4096 + h * 128 + kc * 32 +
                                quad * 8);
    f32x4 o[9] = {};
    float m_[4] = {-INFINITY, -INFINITY, -INFINITY, -INFINITY};
    const int nkt = qt + 1;
    for (int kt = 0; kt < nkt; kt++) {
      const int k0 = kt * 64;
      __syncthreads();  // drains current tile's glds16; protects buf^1
      const int nx = (kt + 1 < nkt) ? k0 + 64 : 0;  // next tile (or tile0 of next phase)
      stage(nx, buf ^ 1);

      const short* Kb = Ks[buf];
      const short* Vb = Vs[buf];
      f32x4 sf[4];
#pragma unroll
      for (int tn = 0; tn < 4; tn++) {
        f32x4 s = {0.f, 0.f, 0.f, 0.f};
#pragma unroll
        for (int kc = 0; kc < 4; kc++) {
          bf16x8 bk = *(const bf16x8*)&Kb[(tn * 16 + l15) * 128 + ((kc * 4 + quad) ^ swz) * 8];
          s = __builtin_amdgcn_mfma_f32_16x16x32_bf16(aq[kc], bk, s, 0, 0, 0);
        }
        sf[tn] = s;
      }

      const bool diag = (kt == qt);
#pragma unroll
      for (int r = 0; r < 4; r++) {
        const int grow = rw + quad * 4 + r;
        float mx = -3.0e38f;
        if (diag) {
#pragma unroll
          for (int tn = 0; tn < 4; tn++) {
            float v = sf[tn][r] * sscale;
            if (k0 + tn * 16 + l15 > grow) v = -3.0e38f;
            sf[tn][r] = v;
            mx = fmaxf(mx, v);
          }
        } else {
#pragma unroll
          for (int tn = 0; tn < 4; tn++) {
            float v = sf[tn][r] * sscale;
            sf[tn][r] = v;
            mx = fmaxf(mx, v);
          }
        }
        mx = dpp_max_step<0x121>(mx);
        mx = dpp_max_step<0x122>(mx);
        mx = dpp_max_step<0x124>(mx);
        mx = dpp_max_step<0x128>(mx);
        const float mo = m_[r];
        const float mn = fmaxf(mo, mx);
        m_[r] = mn;
        const float alpha = __builtin_amdgcn_exp2f(mo - mn);
#pragma unroll
        for (int tn = 0; tn < 4; tn++) {
          float p = __builtin_amdgcn_exp2f(sf[tn][r] - mn);
          Ps[wave][(quad * 4 + r) * 72 + tn * 16 + l15] =
              (short)((__float_as_uint(p) + 0x8000u) >> 16);
        }
        if (__ballot(alpha != 1.0f)) {
#pragma unroll
          for (int t = 0; t < 9; t++) o[t][r] *= alpha;
        }
      }
      // Ps wave-private; same-wave DS ordering suffices (verified round 2)
#pragma unroll
      for (int kk = 0; kk < 2; kk++) {
        bf16x8 ap = *(const bf16x8*)&Ps[wave][l15 * 72 + kk * 32 + quad * 8];
#pragma unroll
        for (int tn = 0; tn < 8; tn++) {
          bf16x8 bv = *(const bf16x8*)&Vb[(tn * 16 + l15) * 64 + ((kk * 4 + quad) ^ swz) * 8];
          o[tn] = __builtin_amdgcn_mfma_f32_16x16x32_bf16(ap, bv, o[tn], 0, 0, 0);
        }
        o[8] = __builtin_amdgcn_mfma_f32_16x16x32_bf16(ap, vone, o[8], 0, 0, 0);  // l
      }
      buf ^= 1;
    }
#pragma unroll
    for (int r = 0; r < 4; r++) {
      const int grow = rw + quad * 4 + r;
      const float sc = vsc / o[8][r];
#pragma unroll
      for (int tn = 0; tn < 8; tn++)
        Oa[(size_t)grow * 4096 + h * 128 + tn * 16 + l15] = f2bf(o[tn][r] * sc);
    }
  }
}

// ---------------- launch ----------------
extern "C" void kernel_launch(void* const* d_in, const int* in_sizes, int n_in,
                              void* d_out, int out_size, void* d_ws, size_t ws_size,
                              hipStream_t stream) {
  (void)in_sizes; (void)n_in; (void)out_size; (void)ws_size;
  const float* H  = (const float*)d_in[0];
  const int*   pos = (const int*)d_in[2];
  const float* wq = (const float*)d_in[3];
  const float* wk = (const float*)d_in[4];
  const float* wv = (const float*)d_in[5];
  const float* wo = (const float*)d_in[6];
  char* ws = (char*)d_ws;
  short* Hb   = (short*)(ws + 0);           // 16 MB
  short* Wt   = (short*)(ws + 16777216);    // 48 MB
  short* Wot  = (short*)(ws + 67108864);    // 32 MB
  float* C    = (float*)(ws + 100663296);   // 48 MB
  short* Qi   = (short*)(ws + 150994944);   // 16 MB
  short* Ki   = (short*)(ws + 167772160);   // 4 MB
  short* Vt   = (short*)(ws + 171966464);   // 4 MB
  short* Oa   = (short*)(ws + 176160768);   // 16 MB
  float* tc   = (float*)(ws + 192937984);   // 512 KB
  float* tsn  = (float*)(ws + 193462272);   // 512 KB
  unsigned* scal = (unsigned*)(ws + 193986560);

  hipLaunchKernelGGL(cast_h, dim3(8192), dim3(256), 0, stream, H, Hb, 2097152);
  hipLaunchKernelGGL(cast_wt, dim3(128, 128), dim3(32, 8), 0, stream, wq, Wt, 4096);
  hipLaunchKernelGGL(cast_wt, dim3(32, 128), dim3(32, 8), 0, stream, wk,
                     Wt + (size_t)4096 * 4096, 1024);
  hipLaunchKernelGGL(cast_wt, dim3(32, 128), dim3(32, 8), 0, stream, wv,
                     Wt + (size_t)5120 * 4096, 1024);
  hipLaunchKernelGGL(cast_wt, dim3(128, 128), dim3(32, 8), 0, stream, wo, Wot, 4096);
  hipLaunchKernelGGL(rope_table, dim3(2048), dim3(64), 0, stream, pos, tc, tsn);
  hipMemsetAsync(scal, 0, 16, stream);
  hipLaunchKernelGGL(gemm_bt, dim3(48, 16), dim3(256), 0, stream, Hb, 4096, Wt, C, 6144,
                     4096);
  hipLaunchKernelGGL(rope_absmax, dim3(2048), dim3(256), 0, stream, C, tc, tsn, scal);
  hipLaunchKernelGGL(quant_q, dim3(32768), dim3(256), 0, stream, C, scal, Qi);
  hipLaunchKernelGGL(quant_k, dim3(8192), dim3(256), 0, stream, C, scal, Ki);
  hipLaunchKernelGGL(quant_vt, dim3(8, 32, 2), dim3(256), 0, stream, C, scal, Vt);
  hipLaunchKernelGGL(attn_fused, dim3(512), dim3(256), 0, stream, Qi, Ki, Vt, scal, Oa);
  hipLaunchKernelGGL(gemm_bt, dim3(32, 16), dim3(256), 0, stream, Oa, 4096, Wot,
                     (float*)d_out, 4096, 4096);
}